// Round 2
// baseline (335.327 us; speedup 1.0000x reference)
//
#include <hip/hip_runtime.h>
#include <hip/hip_fp16.h>

typedef float f32x4 __attribute__((ext_vector_type(4)));
typedef __bf16 bf16x8 __attribute__((ext_vector_type(8)));

#define BB_ 8
#define TT_ 4096
#define DD_ 1024
#define MM_ (BB_*TT_)   // 32768
#define KK_ DD_         // 1024

#define BM 128
#define BN 128
#define BK 32

#define NCH 64
#define LCH (TT_/NCH)   // 64

static __device__ __forceinline__ unsigned short f2bf_rn(float f) {
  unsigned int u = __float_as_uint(f);
  u += 0x7FFFu + ((u >> 16) & 1u);
  return (unsigned short)(u >> 16);
}

// ---------------- conversion: f32 -> bf16 bits (vectorized) ----------------
__global__ void cvt_f32_bf16(const float4* __restrict__ src,
                             ushort4* __restrict__ dst, int n4) {
  int stride = gridDim.x * blockDim.x;
  for (int i = blockIdx.x * blockDim.x + threadIdx.x; i < n4; i += stride) {
    float4 v = src[i];
    ushort4 o;
    o.x = f2bf_rn(v.x); o.y = f2bf_rn(v.y);
    o.z = f2bf_rn(v.z); o.w = f2bf_rn(v.w);
    dst[i] = o;
  }
}

// ---------------- GEMM: 2-phase pipelined + fused epilogue ----------------
__device__ __forceinline__ void gload_lds16(const void* g, void* l) {
  __builtin_amdgcn_global_load_lds(
      (const __attribute__((address_space(1))) void*)g,
      (__attribute__((address_space(3))) void*)l, 16, 0, 0);
}

__global__ __launch_bounds__(256) void gemm_fused(
    const unsigned short* __restrict__ Xb,  // [M][K] bf16 bits
    const unsigned short* __restrict__ Wb,  // [2048][K] bf16 bits (Wz;Wh)
    const float* __restrict__ bz, const float* __restrict__ bh,
    __half* __restrict__ Zb, __half* __restrict__ Gb) // each [M][1024]
{
  __shared__ __align__(16) char smem[32768];
  unsigned short* lA0 = (unsigned short*)(smem);
  unsigned short* lB0 = (unsigned short*)(smem + 8192);
  unsigned short* lA1 = (unsigned short*)(smem + 16384);
  unsigned short* lB1 = (unsigned short*)(smem + 24576);

  const int tid  = threadIdx.x;
  const int wave = tid >> 6;
  const int lane = tid & 63;

  // XCD-aware swizzle: blocks id%8 land on XCD id%8 (round-robin). Give each
  // XCD a contiguous strip of 32 M-tiles x all 16 N-tiles, N fastest.
  int swz = (blockIdx.x & 7) * 512 + (blockIdx.x >> 3);
  const int m0 = (swz >> 4) * BM;
  const int e0 = (swz & 15) * BN;   // 0..2047 in concat space

  const int wr = wave >> 1, wc = wave & 1;
  const int fr = lane & 15;  // fragment row index
  const int kg = lane >> 4;  // k-group 0..3

  // staging addresses (per lane, constant across iters except kk)
  const int il0 = (wave * 2 + 0) * 64 + lane;
  const int il1 = (wave * 2 + 1) * 64 + lane;

  f32x4 acc[4][4];
  #pragma unroll
  for (int i = 0; i < 4; i++)
    #pragma unroll
    for (int j = 0; j < 4; j++)
      acc[i][j] = (f32x4){0.f, 0.f, 0.f, 0.f};

#define STAGE(dA, dB, kkv) do { \
    gload_lds16(Xb + (size_t)(m0 + (il0 >> 2)) * KK_ + (kkv) + (il0 & 3) * 8, \
                (dA) + (size_t)(wave * 2 + 0) * 512); \
    gload_lds16(Wb + (size_t)(e0 + (il0 >> 2)) * KK_ + (kkv) + (il0 & 3) * 8, \
                (dB) + (size_t)(wave * 2 + 0) * 512); \
    gload_lds16(Xb + (size_t)(m0 + (il1 >> 2)) * KK_ + (kkv) + (il1 & 3) * 8, \
                (dA) + (size_t)(wave * 2 + 1) * 512); \
    gload_lds16(Wb + (size_t)(e0 + (il1 >> 2)) * KK_ + (kkv) + (il1 & 3) * 8, \
                (dB) + (size_t)(wave * 2 + 1) * 512); \
  } while (0)

#define COMPUTE(sA, sB) do { \
    bf16x8 af[4], bfv[4]; \
    _Pragma("unroll") \
    for (int i = 0; i < 4; i++) \
      af[i] = *reinterpret_cast<const bf16x8*>(&(sA)[(wr * 64 + i * 16 + fr) * BK + kg * 8]); \
    _Pragma("unroll") \
    for (int j = 0; j < 4; j++) \
      bfv[j] = *reinterpret_cast<const bf16x8*>(&(sB)[(wc * 64 + j * 16 + fr) * BK + kg * 8]); \
    _Pragma("unroll") \
    for (int i = 0; i < 4; i++) \
      _Pragma("unroll") \
      for (int j = 0; j < 4; j++) \
        acc[i][j] = __builtin_amdgcn_mfma_f32_16x16x32_bf16(af[i], bfv[j], acc[i][j], 0, 0, 0); \
  } while (0)

  STAGE(lA0, lB0, 0);
  __syncthreads();                       // drains vmcnt -> tile 0 ready
  int kk = BK;
  #pragma unroll 1
  for (int t = 0; t < 15; ++t) {         // computes tiles 0..29
    STAGE(lA1, lB1, kk);                 // prefetch odd tile
    COMPUTE(lA0, lB0);
    __syncthreads();                     // drains prefetch + protects buffers
    kk += BK;
    STAGE(lA0, lB0, kk);                 // prefetch even tile
    COMPUTE(lA1, lB1);
    __syncthreads();
    kk += BK;
  }
  STAGE(lA1, lB1, 31 * BK);              // tile 31
  COMPUTE(lA0, lB0);                     // tile 30
  __syncthreads();
  COMPUTE(lA1, lB1);                     // tile 31
  __syncthreads();                       // all waves done with smem -> reuse
#undef STAGE
#undef COMPUTE

  // ---- epilogue: bias + activation, LDS re-layout for coalesced stores ----
  const bool isZ = (e0 < DD_);
  const float* bias = isZ ? bz : bh;
  __half* outp = isZ ? Zb : Gb;
  const int ec0 = isZ ? e0 : (e0 - DD_);

  float bv[4];
  #pragma unroll
  for (int j = 0; j < 4; j++) bv[j] = bias[ec0 + wc * 64 + j * 16 + fr];

  __half* eo = (__half*)smem;            // [4 waves][32 rows][72 halfs]
  const int sub  = lane & 7;             // 16B chunk within row
  const int rowr = lane >> 3;            // 0..7

  #pragma unroll
  for (int p = 0; p < 2; ++p) {          // two 32-row passes
    #pragma unroll
    for (int i2 = 0; i2 < 2; ++i2) {
      const int i = p * 2 + i2;
      #pragma unroll
      for (int j = 0; j < 4; j++) {
        #pragma unroll
        for (int r = 0; r < 4; r++) {
          float val = acc[i][j][r] + bv[j];
          float res;
          if (isZ) {
            res = 1.0f / (1.0f + __expf(-val));      // z = sigmoid(k)
          } else {
            res = (val >= 0.0f) ? (val + 0.5f)       // g(th)
                                : (1.0f / (1.0f + __expf(-val)));
          }
          eo[(size_t)wave * 2304 + (i2 * 16 + kg * 4 + r) * 72 + j * 16 + fr] =
              __float2half(res);
        }
      }
    }
    // read back coalesced: 8 lanes x 16B = 128B per row, 8 rows per q-iter
    #pragma unroll
    for (int q = 0; q < 4; ++q) {
      const int rl = q * 8 + rowr;
      uint4 v = *reinterpret_cast<const uint4*>(
          &eo[(size_t)wave * 2304 + rl * 72 + sub * 8]);
      const size_t rg = (size_t)(m0 + wr * 64 + p * 32 + rl);
      *reinterpret_cast<uint4*>(&outp[rg * DD_ + ec0 + wc * 64 + sub * 8]) = v;
    }
  }
}

// ---------------- scan phase A: per-chunk (P,Q) ----------------
__global__ __launch_bounds__(256) void scan_partial(
    const ushort4* __restrict__ Z, const ushort4* __restrict__ G,
    float4* __restrict__ P, float4* __restrict__ Q) {
  const int d4 = threadIdx.x;   // 0..255 -> 4 dims each
  const int c  = blockIdx.x;    // chunk
  const int b  = blockIdx.y;    // batch
  size_t base = ((size_t)b * TT_ + (size_t)c * LCH) * (DD_ / 4) + d4;
  float p0=1.f,p1=1.f,p2=1.f,p3=1.f, q0=0.f,q1=0.f,q2=0.f,q3=0.f;
  for (int t = 0; t < LCH; ++t) {
    ushort4 uz = Z[base + (size_t)t * (DD_ / 4)];
    ushort4 ug = G[base + (size_t)t * (DD_ / 4)];
    float z, g, a;
    z = __half2float(__ushort_as_half(uz.x)); g = __half2float(__ushort_as_half(ug.x));
    a = 1.f - z; p0 *= a; q0 = fmaf(a, q0, z * g);
    z = __half2float(__ushort_as_half(uz.y)); g = __half2float(__ushort_as_half(ug.y));
    a = 1.f - z; p1 *= a; q1 = fmaf(a, q1, z * g);
    z = __half2float(__ushort_as_half(uz.z)); g = __half2float(__ushort_as_half(ug.z));
    a = 1.f - z; p2 *= a; q2 = fmaf(a, q2, z * g);
    z = __half2float(__ushort_as_half(uz.w)); g = __half2float(__ushort_as_half(ug.w));
    a = 1.f - z; p3 *= a; q3 = fmaf(a, q3, z * g);
  }
  size_t o = ((size_t)b * NCH + c) * (DD_ / 4) + d4;
  P[o] = make_float4(p0, p1, p2, p3);
  Q[o] = make_float4(q0, q1, q2, q3);
}

// ---------------- scan phase B: exclusive scan over chunks ----------------
__global__ __launch_bounds__(256) void scan_combine(
    const float4* __restrict__ P, const float4* __restrict__ Q,
    float4* __restrict__ H) {
  const int d4 = threadIdx.x;
  const int b  = blockIdx.x;
  float4 h = make_float4(0.f, 0.f, 0.f, 0.f);
  for (int c = 0; c < NCH; ++c) {
    size_t o = ((size_t)b * NCH + c) * (DD_ / 4) + d4;
    H[o] = h;
    float4 p = P[o], q = Q[o];
    h.x = fmaf(p.x, h.x, q.x);
    h.y = fmaf(p.y, h.y, q.y);
    h.z = fmaf(p.z, h.z, q.z);
    h.w = fmaf(p.w, h.w, q.w);
  }
}

// ---------------- scan phase C: apply + write output ----------------
__global__ __launch_bounds__(256) void scan_apply(
    const ushort4* __restrict__ Z, const ushort4* __restrict__ G,
    const float4* __restrict__ H, float4* __restrict__ out) {
  const int d4 = threadIdx.x;
  const int c  = blockIdx.x;
  const int b  = blockIdx.y;
  float4 h = H[((size_t)b * NCH + c) * (DD_ / 4) + d4];
  size_t base = ((size_t)b * TT_ + (size_t)c * LCH) * (DD_ / 4) + d4;
  for (int t = 0; t < LCH; ++t) {
    ushort4 uz = Z[base + (size_t)t * (DD_ / 4)];
    ushort4 ug = G[base + (size_t)t * (DD_ / 4)];
    float z, g, a;
    z = __half2float(__ushort_as_half(uz.x)); g = __half2float(__ushort_as_half(ug.x));
    a = 1.f - z; h.x = fmaf(a, h.x, z * g);
    z = __half2float(__ushort_as_half(uz.y)); g = __half2float(__ushort_as_half(ug.y));
    a = 1.f - z; h.y = fmaf(a, h.y, z * g);
    z = __half2float(__ushort_as_half(uz.z)); g = __half2float(__ushort_as_half(ug.z));
    a = 1.f - z; h.z = fmaf(a, h.z, z * g);
    z = __half2float(__ushort_as_half(uz.w)); g = __half2float(__ushort_as_half(ug.w));
    a = 1.f - z; h.w = fmaf(a, h.w, z * g);
    out[base + (size_t)t * (DD_ / 4)] = h;
  }
}

extern "C" void kernel_launch(void* const* d_in, const int* in_sizes, int n_in,
                              void* d_out, int out_size, void* d_ws, size_t ws_size,
                              hipStream_t stream) {
  const float* X  = (const float*)d_in[0];  // [8,4096,1024]
  const float* Wz = (const float*)d_in[1];  // [1024,1024]
  const float* bz = (const float*)d_in[2];
  const float* Wh = (const float*)d_in[3];
  const float* bh = (const float*)d_in[4];
  float* out = (float*)d_out;

  const size_t szXb = (size_t)MM_ * DD_ * 2;      // 64 MiB  bf16 X
  const size_t szWb = (size_t)2 * DD_ * DD_ * 2;  //  4 MiB  bf16 (Wz;Wh)
  const size_t szZ  = (size_t)MM_ * DD_ * 2;      // 64 MiB  fp16 each
  const size_t szPQ = (size_t)BB_ * NCH * DD_ * 4;//  2 MiB  each

  char* ws = (char*)d_ws;
  unsigned short *Xb, *Wb;
  __half *Zb, *Gb;
  const size_t needA = szXb + szWb + 2 * szZ + 3 * szPQ;
  if (ws_size >= needA) {
    Xb = (unsigned short*)ws;              ws += szXb;
    Wb = (unsigned short*)ws;              ws += szWb;
  } else {
    // fallback: stage X/W inside d_out (dead after GEMM), scan state in ws
    Xb = (unsigned short*)d_out;
    Wb = (unsigned short*)((char*)d_out + szXb);
  }
  Zb = (__half*)ws;  ws += szZ;
  Gb = (__half*)ws;  ws += szZ;
  float* P = (float*)ws;  ws += szPQ;
  float* Q = (float*)ws;  ws += szPQ;
  float* H = (float*)ws;

  // 1) convert inputs to bf16
  cvt_f32_bf16<<<2048, 256, 0, stream>>>((const float4*)X, (ushort4*)Xb,
                                         (int)((size_t)MM_ * DD_ / 4));
  cvt_f32_bf16<<<512, 256, 0, stream>>>((const float4*)Wz, (ushort4*)Wb,
                                        DD_ * DD_ / 4);
  cvt_f32_bf16<<<512, 256, 0, stream>>>((const float4*)Wh,
                                        (ushort4*)(Wb + (size_t)DD_ * DD_),
                                        DD_ * DD_ / 4);
  // 2) fused GEMM -> z, g  (N = 2048 concat), 1-D grid for XCD swizzle
  gemm_fused<<<(MM_ / BM) * ((2 * DD_) / BN), 256, 0, stream>>>(Xb, Wb, bz, bh, Zb, Gb);

  // 3) chunked linear scan over T
  scan_partial<<<dim3(NCH, BB_), 256, 0, stream>>>((const ushort4*)Zb, (const ushort4*)Gb,
                                                   (float4*)P, (float4*)Q);
  scan_combine<<<BB_, 256, 0, stream>>>((const float4*)P, (const float4*)Q, (float4*)H);
  scan_apply<<<dim3(NCH, BB_), 256, 0, stream>>>((const ushort4*)Zb, (const ushort4*)Gb,
                                                 (const float4*)H, (float4*)out);
}

// Round 3
// 284.258 us; speedup vs baseline: 1.1797x; 1.1797x over previous
//
#include <hip/hip_runtime.h>
#include <hip/hip_fp16.h>

typedef float f32x4 __attribute__((ext_vector_type(4)));
typedef __bf16 bf16x8 __attribute__((ext_vector_type(8)));

#define BB_ 8
#define TT_ 4096
#define DD_ 1024
#define MM_ (BB_*TT_)   // 32768
#define KK_ DD_         // 1024

#define NCH 64
#define LCH (TT_/NCH)   // 64

static __device__ __forceinline__ unsigned short f2bf_rn(float f) {
  unsigned int u = __float_as_uint(f);
  u += 0x7FFFu + ((u >> 16) & 1u);
  return (unsigned short)(u >> 16);
}

// ---------------- conversion: f32 -> bf16 bits (vectorized) ----------------
__global__ void cvt_f32_bf16(const float4* __restrict__ src,
                             ushort4* __restrict__ dst, int n4) {
  int stride = gridDim.x * blockDim.x;
  for (int i = blockIdx.x * blockDim.x + threadIdx.x; i < n4; i += stride) {
    float4 v = src[i];
    ushort4 o;
    o.x = f2bf_rn(v.x); o.y = f2bf_rn(v.y);
    o.z = f2bf_rn(v.z); o.w = f2bf_rn(v.w);
    dst[i] = o;
  }
}

// ---------------- GEMM: 256^2 tile, BK=64, 4-phase counted-vmcnt ----------
__device__ __forceinline__ void gload_lds16(const void* g, void* l) {
  __builtin_amdgcn_global_load_lds(
      (const __attribute__((address_space(1))) void*)g,
      (__attribute__((address_space(3))) void*)l, 16, 0, 0);
}

// Stage a 64-row "round" (8KB) of A or B for K-tile at half-offset kkh.
// Linear LDS dest (global_load_lds requirement); source pre-swizzled so that
// LDS slot s of row r holds global 16B-chunk (s ^ (r&7))  [rule #21].
#define STA(q, nb_, kkh) gload_lds16(pXa + (q) * 65536 + (kkh), (nb_) + (q) * 8192 + wofs)
#define STB(q, nb_, kkh) gload_lds16(pWb + (q) * 65536 + (kkh), (nb_) + 32768 + (q) * 8192 + wofs)

// One phase: quadrant (mh = M-half of wave tile, kh = K-half of BK=64).
// ds_read frags -> stage 2 rounds for next tile -> [counted vmcnt] ->
// barrier -> lgkmcnt(0)+sched_barrier -> setprio(1) 16xMFMA setprio(0) -> barrier.
#define PHASE(cb_, mh, kh, STAGEOPS, WAITOPS) do {                          \
    const char* Ab_ = (cb_);                                                \
    const char* Bb_ = (cb_) + 32768;                                        \
    const int sk_ = (kh) ? sk1 : sk0;                                       \
    bf16x8 af_[4];                                                          \
    _Pragma("unroll")                                                       \
    for (int ii = 0; ii < 4; ++ii)                                          \
      af_[ii] = *reinterpret_cast<const bf16x8*>(                           \
          Ab_ + rA7 + (mh) * 8192 + ii * 2048 + sk_);                       \
    if ((mh) == 0) {                                                        \
      _Pragma("unroll")                                                     \
      for (int j = 0; j < 4; ++j)                                           \
        bfv[j] = *reinterpret_cast<const bf16x8*>(                          \
            Bb_ + rB7 + j * 2048 + sk_);                                    \
    }                                                                       \
    STAGEOPS;                                                               \
    WAITOPS;                                                                \
    __builtin_amdgcn_s_barrier();                                           \
    asm volatile("s_waitcnt lgkmcnt(0)" ::: "memory");                      \
    __builtin_amdgcn_sched_barrier(0);                                      \
    __builtin_amdgcn_s_setprio(1);                                          \
    _Pragma("unroll")                                                       \
    for (int ii = 0; ii < 4; ++ii)                                          \
      _Pragma("unroll")                                                     \
      for (int j = 0; j < 4; ++j)                                           \
        acc[(mh) * 4 + ii][j] = __builtin_amdgcn_mfma_f32_16x16x32_bf16(    \
            af_[ii], bfv[j], acc[(mh) * 4 + ii][j], 0, 0, 0);               \
    __builtin_amdgcn_s_setprio(0);                                          \
    asm volatile("" ::: "memory");                                          \
    __builtin_amdgcn_s_barrier();                                           \
  } while (0)

__global__ __launch_bounds__(512, 2) void gemm_fused(
    const unsigned short* __restrict__ Xb,  // [M][K] bf16 bits
    const unsigned short* __restrict__ Wb,  // [2048][K] bf16 bits (Wz;Wh)
    const float* __restrict__ bz, const float* __restrict__ bh,
    __half* __restrict__ Zb, __half* __restrict__ Gb) // each [M][1024]
{
  extern __shared__ __align__(16) char smem[];   // 2 x (A 32KB + B 32KB)
  const int tid  = threadIdx.x;
  const int wave = tid >> 6;
  const int lane = tid & 63;
  const int wm = wave >> 2, wn = wave & 3;       // 2M x 4N waves
  const int fr = lane & 15, kg = lane >> 4, fx = fr & 7;

  // XCD-bijective swizzle (1024 % 8 == 0); N-fastest within each XCD strip.
  int swz = (blockIdx.x & 7) * 128 + (blockIdx.x >> 3);
  const int m0 = (swz >> 3) * 256;
  const int e0 = (swz & 7) * 256;   // concat-N space (0..1791)

  // staging per-thread constants (pre-swizzled global source)
  const int arow = tid >> 3;                         // 0..63 row within round
  const int aslx = ((tid & 7) ^ (arow & 7)) * 8;     // swizzled 16B-chunk, halfs
  const unsigned short* pXa = Xb + (size_t)(m0 + arow) * KK_ + aslx;
  const unsigned short* pWb = Wb + (size_t)(e0 + arow) * KK_ + aslx;
  const int wofs = wave * 1024;                      // wave slice of round (bytes)

  // ds_read per-thread constants (swizzled read side)
  const int rA7 = (wm * 128 + fr) * 128;             // A row byte offset
  const int rB7 = (wn * 64 + fr) * 128;              // B row byte offset
  const int sk0 = (kg ^ fx) * 16;                    // k-half 0 slot byte
  const int sk1 = sk0 ^ 64;                          // k-half 1 slot byte

  f32x4 acc[8][4];
  #pragma unroll
  for (int i = 0; i < 8; i++)
    #pragma unroll
    for (int j = 0; j < 4; j++)
      acc[i][j] = (f32x4){0.f, 0.f, 0.f, 0.f};
  bf16x8 bfv[4];

  // prologue: stage K-tile 0 into buf0, order A0,A2,B0..B3,A1,A3
  STA(0, smem, 0); STA(2, smem, 0);
  STB(0, smem, 0); STB(1, smem, 0);
  STB(2, smem, 0); STB(3, smem, 0);
  STA(1, smem, 0); STA(3, smem, 0);
  asm volatile("s_waitcnt vmcnt(2)" ::: "memory");   // first 6 rounds landed
  __builtin_amdgcn_s_barrier();

  #pragma unroll 1
  for (int t = 0; t < 15; ++t) {                     // tiles 0..14, prefetch t+1
    char* cb = smem + ((t & 1) << 16);
    char* nb = smem + (((t + 1) & 1) << 16);
    const int kn = (t + 1) * 64;                     // half-elem K offset
    PHASE(cb, 0, 0, {STA(0, nb, kn); STA(2, nb, kn);},
          asm volatile("s_waitcnt vmcnt(2)" ::: "memory"));
    PHASE(cb, 1, 0, {STB(0, nb, kn); STB(1, nb, kn);}, );
    PHASE(cb, 0, 1, {STB(2, nb, kn); STB(3, nb, kn);}, );
    PHASE(cb, 1, 1, {STA(1, nb, kn); STA(3, nb, kn);},
          asm volatile("s_waitcnt vmcnt(2)" ::: "memory"));
  }
  {                                                  // peeled tile 15 (buf1)
    char* cb = smem + 65536;
    PHASE(cb, 0, 0, {}, asm volatile("s_waitcnt vmcnt(0)" ::: "memory"));
    PHASE(cb, 1, 0, {}, );
    PHASE(cb, 0, 1, {}, );
    PHASE(cb, 1, 1, {}, );
  }

  // ---- epilogue: bias + activation, LDS re-layout for coalesced stores ----
  const bool isZ = (e0 < DD_);
  const float* bias = isZ ? bz : bh;
  __half* outp = isZ ? Zb : Gb;
  const int ec0 = (isZ ? e0 : (e0 - DD_)) + wn * 64;

  float bv[4];
  #pragma unroll
  for (int j = 0; j < 4; j++) bv[j] = bias[ec0 + j * 16 + fr];

  __half* ew = (__half*)(smem + wave * 9216);        // per-wave [64][72] halfs
  const int sub = lane & 7, rowr = lane >> 3;

  #pragma unroll
  for (int p = 0; p < 2; ++p) {                      // two 64-row passes
    #pragma unroll
    for (int ii = 0; ii < 4; ++ii) {
      #pragma unroll
      for (int j = 0; j < 4; ++j) {
        #pragma unroll
        for (int r = 0; r < 4; ++r) {
          float val = acc[p * 4 + ii][j][r] + bv[j];
          float res;
          if (isZ) {
            res = 1.0f / (1.0f + __expf(-val));      // z = sigmoid(k)
          } else {
            res = (val >= 0.0f) ? (val + 0.5f)       // g(th)
                                : (1.0f / (1.0f + __expf(-val)));
          }
          ew[(ii * 16 + kg * 4 + r) * 72 + j * 16 + fr] = __float2half(res);
        }
      }
    }
    #pragma unroll
    for (int q = 0; q < 8; ++q) {                    // coalesced readback+store
      int rl = q * 8 + rowr;
      uint4 v = *reinterpret_cast<const uint4*>(&ew[rl * 72 + sub * 8]);
      size_t rg = (size_t)(m0 + wm * 128 + p * 64 + rl);
      *reinterpret_cast<uint4*>(&outp[rg * DD_ + ec0 + sub * 8]) = v;
    }
  }
}

// ---------------- scan phase A: per-chunk (P,Q) ----------------
__global__ __launch_bounds__(256) void scan_partial(
    const ushort4* __restrict__ Z, const ushort4* __restrict__ G,
    float4* __restrict__ P, float4* __restrict__ Q) {
  const int d4 = threadIdx.x;   // 0..255 -> 4 dims each
  const int c  = blockIdx.x;    // chunk
  const int b  = blockIdx.y;    // batch
  size_t base = ((size_t)b * TT_ + (size_t)c * LCH) * (DD_ / 4) + d4;
  float p0=1.f,p1=1.f,p2=1.f,p3=1.f, q0=0.f,q1=0.f,q2=0.f,q3=0.f;
  for (int t = 0; t < LCH; ++t) {
    ushort4 uz = Z[base + (size_t)t * (DD_ / 4)];
    ushort4 ug = G[base + (size_t)t * (DD_ / 4)];
    float z, g, a;
    z = __half2float(__ushort_as_half(uz.x)); g = __half2float(__ushort_as_half(ug.x));
    a = 1.f - z; p0 *= a; q0 = fmaf(a, q0, z * g);
    z = __half2float(__ushort_as_half(uz.y)); g = __half2float(__ushort_as_half(ug.y));
    a = 1.f - z; p1 *= a; q1 = fmaf(a, q1, z * g);
    z = __half2float(__ushort_as_half(uz.z)); g = __half2float(__ushort_as_half(ug.z));
    a = 1.f - z; p2 *= a; q2 = fmaf(a, q2, z * g);
    z = __half2float(__ushort_as_half(uz.w)); g = __half2float(__ushort_as_half(ug.w));
    a = 1.f - z; p3 *= a; q3 = fmaf(a, q3, z * g);
  }
  size_t o = ((size_t)b * NCH + c) * (DD_ / 4) + d4;
  P[o] = make_float4(p0, p1, p2, p3);
  Q[o] = make_float4(q0, q1, q2, q3);
}

// ---------------- scan phase B: exclusive scan over chunks ----------------
__global__ __launch_bounds__(256) void scan_combine(
    const float4* __restrict__ P, const float4* __restrict__ Q,
    float4* __restrict__ H) {
  const int d4 = threadIdx.x;
  const int b  = blockIdx.x;
  float4 h = make_float4(0.f, 0.f, 0.f, 0.f);
  for (int c = 0; c < NCH; ++c) {
    size_t o = ((size_t)b * NCH + c) * (DD_ / 4) + d4;
    H[o] = h;
    float4 p = P[o], q = Q[o];
    h.x = fmaf(p.x, h.x, q.x);
    h.y = fmaf(p.y, h.y, q.y);
    h.z = fmaf(p.z, h.z, q.z);
    h.w = fmaf(p.w, h.w, q.w);
  }
}

// ---------------- scan phase C: apply + write output ----------------
__global__ __launch_bounds__(256) void scan_apply(
    const ushort4* __restrict__ Z, const ushort4* __restrict__ G,
    const float4* __restrict__ H, float4* __restrict__ out) {
  const int d4 = threadIdx.x;
  const int c  = blockIdx.x;
  const int b  = blockIdx.y;
  float4 h = H[((size_t)b * NCH + c) * (DD_ / 4) + d4];
  size_t base = ((size_t)b * TT_ + (size_t)c * LCH) * (DD_ / 4) + d4;
  for (int t = 0; t < LCH; ++t) {
    ushort4 uz = Z[base + (size_t)t * (DD_ / 4)];
    ushort4 ug = G[base + (size_t)t * (DD_ / 4)];
    float z, g, a;
    z = __half2float(__ushort_as_half(uz.x)); g = __half2float(__ushort_as_half(ug.x));
    a = 1.f - z; h.x = fmaf(a, h.x, z * g);
    z = __half2float(__ushort_as_half(uz.y)); g = __half2float(__ushort_as_half(ug.y));
    a = 1.f - z; h.y = fmaf(a, h.y, z * g);
    z = __half2float(__ushort_as_half(uz.z)); g = __half2float(__ushort_as_half(ug.z));
    a = 1.f - z; h.z = fmaf(a, h.z, z * g);
    z = __half2float(__ushort_as_half(uz.w)); g = __half2float(__ushort_as_half(ug.w));
    a = 1.f - z; h.w = fmaf(a, h.w, z * g);
    out[base + (size_t)t * (DD_ / 4)] = h;
  }
}

extern "C" void kernel_launch(void* const* d_in, const int* in_sizes, int n_in,
                              void* d_out, int out_size, void* d_ws, size_t ws_size,
                              hipStream_t stream) {
  const float* X  = (const float*)d_in[0];  // [8,4096,1024]
  const float* Wz = (const float*)d_in[1];  // [1024,1024]
  const float* bz = (const float*)d_in[2];
  const float* Wh = (const float*)d_in[3];
  const float* bh = (const float*)d_in[4];
  float* out = (float*)d_out;

  const size_t szXb = (size_t)MM_ * DD_ * 2;      // 64 MiB  bf16 X
  const size_t szWb = (size_t)2 * DD_ * DD_ * 2;  //  4 MiB  bf16 (Wz;Wh)
  const size_t szZ  = (size_t)MM_ * DD_ * 2;      // 64 MiB  fp16 each
  const size_t szPQ = (size_t)BB_ * NCH * DD_ * 4;//  2 MiB  each

  char* ws = (char*)d_ws;
  unsigned short *Xb, *Wb;
  __half *Zb, *Gb;
  const size_t needA = szXb + szWb + 2 * szZ + 3 * szPQ;
  if (ws_size >= needA) {
    Xb = (unsigned short*)ws;              ws += szXb;
    Wb = (unsigned short*)ws;              ws += szWb;
  } else {
    // fallback: stage X/W inside d_out (dead after GEMM), scan state in ws
    Xb = (unsigned short*)d_out;
    Wb = (unsigned short*)((char*)d_out + szXb);
  }
  Zb = (__half*)ws;  ws += szZ;
  Gb = (__half*)ws;  ws += szZ;
  float* P = (float*)ws;  ws += szPQ;
  float* Q = (float*)ws;  ws += szPQ;
  float* H = (float*)ws;

  // 1) convert inputs to bf16
  cvt_f32_bf16<<<2048, 256, 0, stream>>>((const float4*)X, (ushort4*)Xb,
                                         (int)((size_t)MM_ * DD_ / 4));
  cvt_f32_bf16<<<512, 256, 0, stream>>>((const float4*)Wz, (ushort4*)Wb,
                                        DD_ * DD_ / 4);
  cvt_f32_bf16<<<512, 256, 0, stream>>>((const float4*)Wh,
                                        (ushort4*)(Wb + (size_t)DD_ * DD_),
                                        DD_ * DD_ / 4);
  // 2) fused GEMM -> z, g  (M=32768, N=2048 concat, K=1024), 128KB dyn-LDS
  gemm_fused<<<(MM_ / 256) * ((2 * DD_) / 256), 512, 131072, stream>>>(
      Xb, Wb, bz, bh, Zb, Gb);

  // 3) chunked linear scan over T
  scan_partial<<<dim3(NCH, BB_), 256, 0, stream>>>((const ushort4*)Zb, (const ushort4*)Gb,
                                                   (float4*)P, (float4*)Q);
  scan_combine<<<BB_, 256, 0, stream>>>((const float4*)P, (const float4*)Q, (float4*)H);
  scan_apply<<<dim3(NCH, BB_), 256, 0, stream>>>((const ushort4*)Zb, (const ushort4*)Gb,
                                                 (const float4*)H, (float4*)out);
}

// Round 4
// 280.071 us; speedup vs baseline: 1.1973x; 1.0150x over previous
//
#include <hip/hip_runtime.h>
#include <hip/hip_fp16.h>

typedef float f32x4 __attribute__((ext_vector_type(4)));
typedef __bf16 bf16x8 __attribute__((ext_vector_type(8)));

#define BB_ 8
#define TT_ 4096
#define DD_ 1024
#define MM_ (BB_*TT_)   // 32768
#define KK_ DD_         // 1024

#define NCH 64
#define LCH (TT_/NCH)   // 64

static __device__ __forceinline__ unsigned short f2bf_rn(float f) {
  unsigned int u = __float_as_uint(f);
  u += 0x7FFFu + ((u >> 16) & 1u);
  return (unsigned short)(u >> 16);
}

// ---------------- conversion: f32 -> bf16 bits (vectorized) ----------------
__global__ void cvt_f32_bf16(const float4* __restrict__ src,
                             ushort4* __restrict__ dst, int n4) {
  int stride = gridDim.x * blockDim.x;
  for (int i = blockIdx.x * blockDim.x + threadIdx.x; i < n4; i += stride) {
    float4 v = src[i];
    ushort4 o;
    o.x = f2bf_rn(v.x); o.y = f2bf_rn(v.y);
    o.z = f2bf_rn(v.z); o.w = f2bf_rn(v.w);
    dst[i] = o;
  }
}

// ---------------- GEMM: 256^2 tile, BK=64, 4-phase counted-vmcnt ----------
__device__ __forceinline__ void gload_lds16(const void* g, void* l) {
  __builtin_amdgcn_global_load_lds(
      (const __attribute__((address_space(1))) void*)g,
      (__attribute__((address_space(3))) void*)l, 16, 0, 0);
}

// Stage a 64-row "round" (8KB) of A or B for K-tile at half-offset kkh.
// Linear LDS dest (global_load_lds requirement); source pre-swizzled so that
// LDS slot s of row r holds global 16B-chunk (s ^ (r&7))  [rule #21].
#define STA(q, nb_, kkh) gload_lds16(pXa + (q) * 65536 + (kkh), (nb_) + (q) * 8192 + wofs)
#define STB(q, nb_, kkh) gload_lds16(pWb + (q) * 65536 + (kkh), (nb_) + 32768 + (q) * 8192 + wofs)

// One phase: quadrant (mh = M-half of wave tile, kh = K-half of BK=64).
// ds_read frags -> stage rounds for next tile -> [counted vmcnt] ->
// barrier -> lgkmcnt(0)+sched_barrier -> setprio(1) 16xMFMA setprio(0) -> barrier.
// Wait ledger (distance >= 2 phases for every covered load):
//   issue: ph0 A0',A2',B0' | ph1 B1',B2',B3' | ph2 A1',A3' | ph3 --
//   wait:  ph0 vmcnt(3) covers A1,A3 (read next phase, issued prev-iter ph2)
//          ph3 vmcnt(2) covers next tile's A0,A2,B0..B3 (latest issued ph1)
#define PHASE(cb_, mh, kh, STAGEOPS, WAITOPS) do {                          \
    const char* Ab_ = (cb_);                                                \
    const char* Bb_ = (cb_) + 32768;                                        \
    const int sk_ = (kh) ? sk1 : sk0;                                       \
    bf16x8 af_[4];                                                          \
    _Pragma("unroll")                                                       \
    for (int ii = 0; ii < 4; ++ii)                                          \
      af_[ii] = *reinterpret_cast<const bf16x8*>(                           \
          Ab_ + rA7 + (mh) * 8192 + ii * 2048 + sk_);                       \
    if ((mh) == 0) {                                                        \
      _Pragma("unroll")                                                     \
      for (int j = 0; j < 4; ++j)                                           \
        bfv[j] = *reinterpret_cast<const bf16x8*>(                          \
            Bb_ + rB7 + j * 2048 + sk_);                                    \
    }                                                                       \
    STAGEOPS;                                                               \
    WAITOPS;                                                                \
    __builtin_amdgcn_s_barrier();                                           \
    asm volatile("s_waitcnt lgkmcnt(0)" ::: "memory");                      \
    __builtin_amdgcn_sched_barrier(0);                                      \
    __builtin_amdgcn_s_setprio(1);                                          \
    _Pragma("unroll")                                                       \
    for (int ii = 0; ii < 4; ++ii)                                          \
      _Pragma("unroll")                                                     \
      for (int j = 0; j < 4; ++j)                                           \
        acc[(mh) * 4 + ii][j] = __builtin_amdgcn_mfma_f32_16x16x32_bf16(    \
            af_[ii], bfv[j], acc[(mh) * 4 + ii][j], 0, 0, 0);               \
    __builtin_amdgcn_s_setprio(0);                                          \
    asm volatile("" ::: "memory");                                          \
    __builtin_amdgcn_s_barrier();                                           \
  } while (0)

__global__ __launch_bounds__(512, 2) void gemm_fused(
    const unsigned short* __restrict__ Xb,  // [M][K] bf16 bits
    const unsigned short* __restrict__ Wb,  // [2048][K] bf16 bits (Wz;Wh)
    const float* __restrict__ bz, const float* __restrict__ bh,
    __half* __restrict__ Zb, __half* __restrict__ Gb) // each [M][1024]
{
  extern __shared__ __align__(16) char smem[];   // 2 x (A 32KB + B 32KB)
  const int tid  = threadIdx.x;
  const int wave = tid >> 6;
  const int lane = tid & 63;
  const int wm = wave >> 2, wn = wave & 3;       // 2M x 4N waves
  const int fr = lane & 15, kg = lane >> 4, fx = fr & 7;

  // XCD-bijective swizzle (1024 % 8 == 0); N-fastest within each XCD strip.
  int swz = (blockIdx.x & 7) * 128 + (blockIdx.x >> 3);
  const int m0 = (swz >> 3) * 256;
  const int e0 = (swz & 7) * 256;   // concat-N space (0..1791)

  // staging per-thread constants (pre-swizzled global source)
  const int arow = tid >> 3;                         // 0..63 row within round
  const int aslx = ((tid & 7) ^ (arow & 7)) * 8;     // swizzled 16B-chunk, halfs
  const unsigned short* pXa = Xb + (size_t)(m0 + arow) * KK_ + aslx;
  const unsigned short* pWb = Wb + (size_t)(e0 + arow) * KK_ + aslx;
  const int wofs = wave * 1024;                      // wave slice of round (bytes)

  // ds_read per-thread constants (swizzled read side)
  const int rA7 = (wm * 128 + fr) * 128;             // A row byte offset
  const int rB7 = (wn * 64 + fr) * 128;              // B row byte offset
  const int sk0 = (kg ^ fx) * 16;                    // k-half 0 slot byte
  const int sk1 = sk0 ^ 64;                          // k-half 1 slot byte

  f32x4 acc[8][4];
  #pragma unroll
  for (int i = 0; i < 8; i++)
    #pragma unroll
    for (int j = 0; j < 4; j++)
      acc[i][j] = (f32x4){0.f, 0.f, 0.f, 0.f};
  bf16x8 bfv[4];

  // prologue: stage K-tile 0 into buf0
  STA(0, smem, 0); STA(2, smem, 0); STB(0, smem, 0);
  STB(1, smem, 0); STB(2, smem, 0); STB(3, smem, 0);
  STA(1, smem, 0); STA(3, smem, 0);
  asm volatile("s_waitcnt vmcnt(2)" ::: "memory");   // first 6 rounds landed
  __builtin_amdgcn_s_barrier();

  #pragma unroll 1
  for (int t = 0; t < 15; ++t) {                     // tiles 0..14, prefetch t+1
    char* cb = smem + ((t & 1) << 16);
    char* nb = smem + (((t + 1) & 1) << 16);
    const int kn = (t + 1) * 64;                     // half-elem K offset
    PHASE(cb, 0, 0, {STA(0, nb, kn); STA(2, nb, kn); STB(0, nb, kn);},
          asm volatile("s_waitcnt vmcnt(3)" ::: "memory"));
    PHASE(cb, 1, 0, {STB(1, nb, kn); STB(2, nb, kn); STB(3, nb, kn);}, );
    PHASE(cb, 0, 1, {STA(1, nb, kn); STA(3, nb, kn);}, );
    PHASE(cb, 1, 1, {},
          asm volatile("s_waitcnt vmcnt(2)" ::: "memory"));
  }
  {                                                  // peeled tile 15 (buf1)
    char* cb = smem + 65536;
    PHASE(cb, 0, 0, {}, asm volatile("s_waitcnt vmcnt(0)" ::: "memory"));
    PHASE(cb, 1, 0, {}, );
    PHASE(cb, 0, 1, {}, );
    PHASE(cb, 1, 1, {}, );
  }

  // ---- epilogue: bias + activation, LDS re-layout for coalesced stores ----
  const bool isZ = (e0 < DD_);
  const float* bias = isZ ? bz : bh;
  __half* outp = isZ ? Zb : Gb;
  const int ec0 = (isZ ? e0 : (e0 - DD_)) + wn * 64;

  float bv[4];
  #pragma unroll
  for (int j = 0; j < 4; j++) bv[j] = bias[ec0 + j * 16 + fr];

  __half* ew = (__half*)(smem + wave * 9216);        // per-wave [64][72] halfs
  const int sub = lane & 7, rowr = lane >> 3;

  #pragma unroll
  for (int p = 0; p < 2; ++p) {                      // two 64-row passes
    #pragma unroll
    for (int ii = 0; ii < 4; ++ii) {
      #pragma unroll
      for (int j = 0; j < 4; ++j) {
        #pragma unroll
        for (int r = 0; r < 4; ++r) {
          float val = acc[p * 4 + ii][j][r] + bv[j];
          float res;
          if (isZ) {
            res = 1.0f / (1.0f + __expf(-val));      // z = sigmoid(k)
          } else {
            res = (val >= 0.0f) ? (val + 0.5f)       // g(th)
                                : (1.0f / (1.0f + __expf(-val)));
          }
          ew[(ii * 16 + kg * 4 + r) * 72 + j * 16 + fr] = __float2half(res);
        }
      }
    }
    #pragma unroll
    for (int q = 0; q < 8; ++q) {                    // coalesced readback+store
      int rl = q * 8 + rowr;
      uint4 v = *reinterpret_cast<const uint4*>(&ew[rl * 72 + sub * 8]);
      size_t rg = (size_t)(m0 + wm * 128 + p * 64 + rl);
      *reinterpret_cast<uint4*>(&outp[rg * DD_ + ec0 + sub * 8]) = v;
    }
  }
}

// ---------------- scan phase A: per-chunk (P,Q) ----------------
__global__ __launch_bounds__(256) void scan_partial(
    const ushort4* __restrict__ Z, const ushort4* __restrict__ G,
    float4* __restrict__ P, float4* __restrict__ Q) {
  const int d4 = threadIdx.x;   // 0..255 -> 4 dims each
  const int c  = blockIdx.x;    // chunk
  const int b  = blockIdx.y;    // batch
  size_t base = ((size_t)b * TT_ + (size_t)c * LCH) * (DD_ / 4) + d4;
  float p0=1.f,p1=1.f,p2=1.f,p3=1.f, q0=0.f,q1=0.f,q2=0.f,q3=0.f;
  for (int t = 0; t < LCH; ++t) {
    ushort4 uz = Z[base + (size_t)t * (DD_ / 4)];
    ushort4 ug = G[base + (size_t)t * (DD_ / 4)];
    float z, g, a;
    z = __half2float(__ushort_as_half(uz.x)); g = __half2float(__ushort_as_half(ug.x));
    a = 1.f - z; p0 *= a; q0 = fmaf(a, q0, z * g);
    z = __half2float(__ushort_as_half(uz.y)); g = __half2float(__ushort_as_half(ug.y));
    a = 1.f - z; p1 *= a; q1 = fmaf(a, q1, z * g);
    z = __half2float(__ushort_as_half(uz.z)); g = __half2float(__ushort_as_half(ug.z));
    a = 1.f - z; p2 *= a; q2 = fmaf(a, q2, z * g);
    z = __half2float(__ushort_as_half(uz.w)); g = __half2float(__ushort_as_half(ug.w));
    a = 1.f - z; p3 *= a; q3 = fmaf(a, q3, z * g);
  }
  size_t o = ((size_t)b * NCH + c) * (DD_ / 4) + d4;
  P[o] = make_float4(p0, p1, p2, p3);
  Q[o] = make_float4(q0, q1, q2, q3);
}

// ---------------- scan phase B: exclusive scan over chunks ----------------
__global__ __launch_bounds__(256) void scan_combine(
    const float4* __restrict__ P, const float4* __restrict__ Q,
    float4* __restrict__ H) {
  const int d4 = threadIdx.x;
  const int b  = blockIdx.x;
  float4 h = make_float4(0.f, 0.f, 0.f, 0.f);
  for (int c = 0; c < NCH; ++c) {
    size_t o = ((size_t)b * NCH + c) * (DD_ / 4) + d4;
    H[o] = h;
    float4 p = P[o], q = Q[o];
    h.x = fmaf(p.x, h.x, q.x);
    h.y = fmaf(p.y, h.y, q.y);
    h.z = fmaf(p.z, h.z, q.z);
    h.w = fmaf(p.w, h.w, q.w);
  }
}

// ---------------- scan phase C: apply + write output ----------------
__global__ __launch_bounds__(256) void scan_apply(
    const ushort4* __restrict__ Z, const ushort4* __restrict__ G,
    const float4* __restrict__ H, float4* __restrict__ out) {
  const int d4 = threadIdx.x;
  const int c  = blockIdx.x;
  const int b  = blockIdx.y;
  float4 h = H[((size_t)b * NCH + c) * (DD_ / 4) + d4];
  size_t base = ((size_t)b * TT_ + (size_t)c * LCH) * (DD_ / 4) + d4;
  for (int t = 0; t < LCH; ++t) {
    ushort4 uz = Z[base + (size_t)t * (DD_ / 4)];
    ushort4 ug = G[base + (size_t)t * (DD_ / 4)];
    float z, g, a;
    z = __half2float(__ushort_as_half(uz.x)); g = __half2float(__ushort_as_half(ug.x));
    a = 1.f - z; h.x = fmaf(a, h.x, z * g);
    z = __half2float(__ushort_as_half(uz.y)); g = __half2float(__ushort_as_half(ug.y));
    a = 1.f - z; h.y = fmaf(a, h.y, z * g);
    z = __half2float(__ushort_as_half(uz.z)); g = __half2float(__ushort_as_half(ug.z));
    a = 1.f - z; h.z = fmaf(a, h.z, z * g);
    z = __half2float(__ushort_as_half(uz.w)); g = __half2float(__ushort_as_half(ug.w));
    a = 1.f - z; h.w = fmaf(a, h.w, z * g);
    out[base + (size_t)t * (DD_ / 4)] = h;
  }
}

extern "C" void kernel_launch(void* const* d_in, const int* in_sizes, int n_in,
                              void* d_out, int out_size, void* d_ws, size_t ws_size,
                              hipStream_t stream) {
  const float* X  = (const float*)d_in[0];  // [8,4096,1024]
  const float* Wz = (const float*)d_in[1];  // [1024,1024]
  const float* bz = (const float*)d_in[2];
  const float* Wh = (const float*)d_in[3];
  const float* bh = (const float*)d_in[4];
  float* out = (float*)d_out;

  const size_t szXb = (size_t)MM_ * DD_ * 2;      // 64 MiB  bf16 X
  const size_t szWb = (size_t)2 * DD_ * DD_ * 2;  //  4 MiB  bf16 (Wz;Wh)
  const size_t szZ  = (size_t)MM_ * DD_ * 2;      // 64 MiB  fp16 each
  const size_t szPQ = (size_t)BB_ * NCH * DD_ * 4;//  2 MiB  each

  char* ws = (char*)d_ws;
  unsigned short *Xb, *Wb;
  __half *Zb, *Gb;
  const size_t needA = szXb + szWb + 2 * szZ + 3 * szPQ;
  if (ws_size >= needA) {
    Xb = (unsigned short*)ws;              ws += szXb;
    Wb = (unsigned short*)ws;              ws += szWb;
  } else {
    // fallback: stage X/W inside d_out (dead after GEMM), scan state in ws
    Xb = (unsigned short*)d_out;
    Wb = (unsigned short*)((char*)d_out + szXb);
  }
  Zb = (__half*)ws;  ws += szZ;
  Gb = (__half*)ws;  ws += szZ;
  float* P = (float*)ws;  ws += szPQ;
  float* Q = (float*)ws;  ws += szPQ;
  float* H = (float*)ws;

  // 1) convert inputs to bf16
  cvt_f32_bf16<<<2048, 256, 0, stream>>>((const float4*)X, (ushort4*)Xb,
                                         (int)((size_t)MM_ * DD_ / 4));
  cvt_f32_bf16<<<512, 256, 0, stream>>>((const float4*)Wz, (ushort4*)Wb,
                                        DD_ * DD_ / 4);
  cvt_f32_bf16<<<512, 256, 0, stream>>>((const float4*)Wh,
                                        (ushort4*)(Wb + (size_t)DD_ * DD_),
                                        DD_ * DD_ / 4);
  // 2) fused GEMM -> z, g  (M=32768, N=2048 concat, K=1024), 128KB dyn-LDS
  gemm_fused<<<(MM_ / 256) * ((2 * DD_) / 256), 512, 131072, stream>>>(
      Xb, Wb, bz, bh, Zb, Gb);

  // 3) chunked linear scan over T
  scan_partial<<<dim3(NCH, BB_), 256, 0, stream>>>((const ushort4*)Zb, (const ushort4*)Gb,
                                                   (float4*)P, (float4*)Q);
  scan_combine<<<BB_, 256, 0, stream>>>((const float4*)P, (const float4*)Q, (float4*)H);
  scan_apply<<<dim3(NCH, BB_), 256, 0, stream>>>((const ushort4*)Zb, (const ushort4*)Gb,
                                                 (const float4*)H, (float4*)out);
}